// Round 1
// baseline (101.199 us; speedup 1.0000x reference)
//
#include <hip/hip_runtime.h>
#include <hip/hip_bf16.h>

#define LOG2E 1.4426950408889634f

typedef __bf16 bf16x8 __attribute__((ext_vector_type(8)));
typedef float  f32x4  __attribute__((ext_vector_type(4)));

// 2 f32 -> packed 2x bf16 (RNE); compiler emits v_cvt_pk_bf16_f32
__device__ inline unsigned cvt2(float lo, float hi){
  __hip_bfloat162 h = __float22bfloat162_rn(make_float2(lo, hi));
  return *reinterpret_cast<unsigned*>(&h);
}

// Fused single kernel. Block = (b, j-half): grid 128 = 64 b * 2 jh, 1024 thr (16 waves).
// Phase A: mat_b = X @ W[:, b*16..+16]  (256x16 f32) -> LDS L, via MFMA.
//   wave w computes rows [w*16, +16): A-frags straight from global X (L2-hot),
//   B-frags from Bs (W-slice transposed to [c][k] bf16, XOR-swizzled 16B chunks).
// Phase B: out[j][b] = bias[b] + sum_i exp(-sum_c |L[i][c]-L[j][c]|), j in [jh*128,+128).
// No workspace, no inter-block dependencies, one launch.
__global__ __launch_bounds__(1024) void k_fused(const float* __restrict__ X,
                                                const float* __restrict__ Wm,
                                                const float* __restrict__ bias,
                                                float* __restrict__ out){
  // Bs element (k,c) at u16 index: (k>>3)*128 + ((c ^ ((k>>3)&7)) * 8) + (k&7)
  // -> frag read (fixed k-block, c = lane&15) is 256B contiguous per 16-lane group.
  __shared__ unsigned short Bs[16 * 1024];   // 32 KB
  __shared__ float L[256 * 20];              // 20 KB, row stride 20 (16B-aligned rows)
  __shared__ float red[8][128];              // 4 KB

  const int b  = blockIdx.x >> 1;
  const int jh = blockIdx.x & 1;
  const int t = threadIdx.x, lane = t & 63, w = t >> 6;
  const int r16 = lane & 15, quad = lane >> 4;

  { // ---- stage W[:, b*16..+16] -> Bs (bf16, transpose + swizzle), one-time
    const int kp = t & 511, ch = t >> 9;         // k-pair index, col-half (8 cols each)
    const int k0 = kp * 2;
    const int kb = k0 >> 3, ks8 = (k0 & 7);      // swizzle block, slot (even)
    const float* wp = Wm + (size_t)k0 * 1024 + b * 16 + ch * 8;
    float4 w00 = *(const float4*)(wp);           // row k0,   cols ch*8+0..3
    float4 w01 = *(const float4*)(wp + 4);       // row k0,   cols ch*8+4..7
    float4 w10 = *(const float4*)(wp + 1024);    // row k0+1, cols ch*8+0..3
    float4 w11 = *(const float4*)(wp + 1028);    // row k0+1, cols ch*8+4..7
    const float* a0 = (const float*)&w00;
    const float* a1 = (const float*)&w10;
    const float* c0 = (const float*)&w01;
    const float* c1 = (const float*)&w11;
    #pragma unroll
    for (int e = 0; e < 4; ++e){
      const int ca = ch * 8 + e;
      *(unsigned*)&Bs[kb * 128 + ((ca ^ (kb & 7)) * 8) + ks8] = cvt2(a0[e], a1[e]);
      const int cb = ch * 8 + 4 + e;
      *(unsigned*)&Bs[kb * 128 + ((cb ^ (kb & 7)) * 8) + ks8] = cvt2(c0[e], c1[e]);
    }
  }
  __syncthreads();

  // ---- Phase A: per-wave GEMM, 32 chained MFMAs over K=1024
  f32x4 acc;
  acc[0] = acc[1] = acc[2] = acc[3] = 0.f;
  const float* xp = X + (size_t)(w * 16 + r16) * 1024 + quad * 8;
  #pragma unroll 4
  for (int ks = 0; ks < 32; ++ks){
    float4 x0 = *(const float4*)(xp + ks * 32);
    float4 x1 = *(const float4*)(xp + ks * 32 + 4);
    union { unsigned u[4]; bf16x8 v; } A;
    A.u[0] = cvt2(x0.x, x0.y); A.u[1] = cvt2(x0.z, x0.w);
    A.u[2] = cvt2(x1.x, x1.y); A.u[3] = cvt2(x1.z, x1.w);
    const int kb = ks * 4 + quad;                // k/8 block for this lane's 8 k's
    bf16x8 Bf = *(const bf16x8*)&Bs[kb * 128 + ((r16 ^ (kb & 7)) * 8)];
    acc = __builtin_amdgcn_mfma_f32_16x16x32_bf16(A.v, Bf, acc, 0, 0, 0);
  }
  // C/D layout (verified lineage): col = lane&15, row = (lane>>4)*4 + reg
  #pragma unroll
  for (int r = 0; r < 4; ++r)
    L[(w * 16 + quad * 4 + r) * 20 + r16] = acc[r];
  __syncthreads();

  // ---- Phase B: pairwise exp(-L1). wave -> (j-group of 64, i-group of 32)
  const int jg = w & 1, ig = w >> 1;
  const int j = jh * 128 + jg * 64 + lane;
  float oj[16];
  #pragma unroll
  for (int q = 0; q < 4; ++q){
    float4 v = *(const float4*)(&L[j * 20 + q * 4]);
    oj[q*4+0] = v.x; oj[q*4+1] = v.y; oj[q*4+2] = v.z; oj[q*4+3] = v.w;
  }
  float accs = 0.f;
  const int i0 = ig * 32;
  #pragma unroll 4
  for (int ii = i0; ii < i0 + 32; ++ii){
    const float4* fr = (const float4*)(&L[ii * 20]);   // wave-uniform -> broadcast
    float4 f0 = fr[0], f1 = fr[1], f2 = fr[2], f3 = fr[3];
    float p0 = fabsf(oj[0]  - f0.x) + fabsf(oj[1]  - f0.y)
             + fabsf(oj[2]  - f0.z) + fabsf(oj[3]  - f0.w);
    float p1 = fabsf(oj[4]  - f1.x) + fabsf(oj[5]  - f1.y)
             + fabsf(oj[6]  - f1.z) + fabsf(oj[7]  - f1.w);
    float p2 = fabsf(oj[8]  - f2.x) + fabsf(oj[9]  - f2.y)
             + fabsf(oj[10] - f2.z) + fabsf(oj[11] - f2.w);
    float p3 = fabsf(oj[12] - f3.x) + fabsf(oj[13] - f3.y)
             + fabsf(oj[14] - f3.z) + fabsf(oj[15] - f3.w);
    accs += exp2f(-LOG2E * ((p0 + p1) + (p2 + p3)));
  }
  red[ig][jg * 64 + lane] = accs;
  __syncthreads();
  if (t < 128){
    float tot = 0.f;
    #pragma unroll
    for (int p = 0; p < 8; ++p) tot += red[p][t];
    out[(size_t)(jh * 128 + t) * 64 + b] = tot + bias[b];
  }
}

extern "C" void kernel_launch(void* const* d_in, const int* in_sizes, int n_in,
                              void* d_out, int out_size, void* d_ws, size_t ws_size,
                              hipStream_t stream){
  const float* x    = (const float*)d_in[0];   // [256][1024]
  const float* W    = (const float*)d_in[1];   // [1024][1024]
  const float* bias = (const float*)d_in[2];   // [64]
  float* out = (float*)d_out;                  // [256][64]
  (void)d_ws; (void)ws_size;

  k_fused<<<dim3(128), dim3(1024), 0, stream>>>(x, W, bias, out);
}

// Round 2
// 74.123 us; speedup vs baseline: 1.3653x; 1.3653x over previous
//
#include <hip/hip_runtime.h>

#define LOG2E 1.4426950408889634f

typedef __bf16 bf16x8 __attribute__((ext_vector_type(8)));
typedef float  f32x4  __attribute__((ext_vector_type(4)));

__device__ inline unsigned short f2bf(float f){
  unsigned u = __float_as_uint(f);
  unsigned r = u + 0x7FFFu + ((u >> 16) & 1u);   // RNE; inputs finite
  return (unsigned short)(r >> 16);
}
__device__ inline unsigned pack2(float lo, float hi){
  return (unsigned)f2bf(lo) | ((unsigned)f2bf(hi) << 16);
}

// ---- K1: K-split GEMM.  P[ks][b][i][c] f32 partial (b-major so K2 reads stream).
// grid (4 m-tiles, 16 n-tiles, 4 k-splits) = 256 blocks (1/CU), 256 thr.
// f32->bf16 convert + W transpose fused into LDS staging; reg prefetch 1 iter ahead.
// All global reads coalesced (X: 64B/16-lane segs; W: 256B/16-lane segs).
__global__ __launch_bounds__(256) void k_gemm_ks(const float* __restrict__ X,
                                                 const float* __restrict__ Wm,
                                                 float* __restrict__ P){
  __shared__ unsigned short As[64 * 72];   // [m][k] bf16, row stride 72
  __shared__ unsigned short Bs[64 * 72];   // [n][k] bf16, XOR-chunk swizzled
  const int m0 = blockIdx.x * 64, n0 = blockIdx.y * 64;
  const int k0 = blockIdx.z * 256;
  const int t = threadIdx.x;
  const int lane = t & 63, w = t >> 6;
  const int wrow = (w & 1) * 32, wcol = (w >> 1) * 32;
  const int r16 = lane & 15, quad = lane >> 4;

  const int ar = t >> 2, aq = t & 3;          // A: row 0..63, 16-float quarter
  const int bc = t & 15, bg = t >> 4;         // B: 4-col group, 4-krow group
  const float* ap = X + (size_t)(m0 + ar) * 1024 + k0 + aq * 16;
  const float* bp = Wm + (size_t)k0 * 1024 + n0 + bc * 4;

  f32x4 acc[2][2];
  #pragma unroll
  for (int p = 0; p < 2; ++p)
    #pragma unroll
    for (int q = 0; q < 2; ++q)
      #pragma unroll
      for (int e = 0; e < 4; ++e) acc[p][q][e] = 0.f;

  float4 pa[4], pb[4];
  #pragma unroll
  for (int r = 0; r < 4; ++r) pa[r] = *(const float4*)(ap + r * 4);
  #pragma unroll
  for (int r = 0; r < 4; ++r) pb[r] = *(const float4*)(bp + (size_t)(4 * bg + r) * 1024);

  #pragma unroll
  for (int kt = 0; kt < 256; kt += 64){
    __syncthreads();                          // prev iter's ds_reads done
    { // A tile: 16 floats -> 16 bf16, contiguous store
      unsigned short* d = &As[ar * 72 + aq * 16];
      uint4 o;
      o.x = pack2(pa[0].x, pa[0].y); o.y = pack2(pa[0].z, pa[0].w);
      o.z = pack2(pa[1].x, pa[1].y); o.w = pack2(pa[1].z, pa[1].w);
      *(uint4*)d = o;
      o.x = pack2(pa[2].x, pa[2].y); o.y = pack2(pa[2].z, pa[2].w);
      o.z = pack2(pa[3].x, pa[3].y); o.w = pack2(pa[3].z, pa[3].w);
      *(uint4*)(d + 8) = o;
    }
    { // B tile: transpose 4 k-rows x 4 n-cols into [n][k], swizzled 8-bf16 chunks
      #pragma unroll
      for (int e = 0; e < 4; ++e){
        const int n = bc * 4 + e;
        uint2 o;
        o.x = pack2(((const float*)&pb[0])[e], ((const float*)&pb[1])[e]);
        o.y = pack2(((const float*)&pb[2])[e], ((const float*)&pb[3])[e]);
        const int cw = (bg >> 1) ^ ((n >> 3) & 7);
        *(uint2*)(&Bs[n * 72 + cw * 8 + (bg & 1) * 4]) = o;
      }
    }
    __syncthreads();
    if (kt < 192){                            // prefetch next k-tile into regs
      #pragma unroll
      for (int r = 0; r < 4; ++r) pa[r] = *(const float4*)(ap + kt + 64 + r * 4);
      #pragma unroll
      for (int r = 0; r < 4; ++r) pb[r] = *(const float4*)(bp + (size_t)(kt + 64 + 4 * bg + r) * 1024);
    }
    #pragma unroll
    for (int kk = 0; kk < 2; ++kk){
      const int ko = kk * 32 + quad * 8;
      bf16x8 a0 = *(const bf16x8*)(&As[(wrow      + r16) * 72 + ko]);
      bf16x8 a1 = *(const bf16x8*)(&As[(wrow + 16 + r16) * 72 + ko]);
      const int c = kk * 4 + quad;
      const int nb0 = wcol + r16, nb1 = wcol + 16 + r16;
      bf16x8 b0 = *(const bf16x8*)(&Bs[nb0 * 72 + ((c ^ ((nb0 >> 3) & 7)) * 8)]);
      bf16x8 b1 = *(const bf16x8*)(&Bs[nb1 * 72 + ((c ^ ((nb1 >> 3) & 7)) * 8)]);
      acc[0][0] = __builtin_amdgcn_mfma_f32_16x16x32_bf16(a0, b0, acc[0][0], 0, 0, 0);
      acc[0][1] = __builtin_amdgcn_mfma_f32_16x16x32_bf16(a0, b1, acc[0][1], 0, 0, 0);
      acc[1][0] = __builtin_amdgcn_mfma_f32_16x16x32_bf16(a1, b0, acc[1][0], 0, 0, 0);
      acc[1][1] = __builtin_amdgcn_mfma_f32_16x16x32_bf16(a1, b1, acc[1][1], 0, 0, 0);
    }
  }
  // C/D layout (verified): col = lane&15, row = (lane>>4)*4 + reg
  // b-major epilogue: P[ks][col>>4][row][col&15]; col&15 == r16
  float* Pz = P + (size_t)blockIdx.z * 64 * 256 * 16;
  #pragma unroll
  for (int p = 0; p < 2; ++p)
    #pragma unroll
    for (int q = 0; q < 2; ++q)
      #pragma unroll
      for (int r = 0; r < 4; ++r){
        const int row = m0 + wrow + p * 16 + quad * 4 + r;
        const int col = n0 + wcol + q * 16 + r16;
        Pz[(size_t)(col >> 4) * 4096 + row * 16 + (col & 15)] = acc[p][q][r];
      }
}

// ---- K2: out[j][b] = bias[b] + sum_i exp(-sum_c |mat[i,b,c]-mat[j,b,c]|)
// grid 256 = 64 b * 4 j-chunks; 1024 thr = 16 waves; wave w owns i in [w*16,+16).
// Staging sums the 4 K-split partials from b-major P: four contiguous 16 KB
// streams per block (thread t -> P + b*4096 + t*4), fully coalesced.
__global__ __launch_bounds__(1024) void k_pair(const float* __restrict__ P,
                                               const float* __restrict__ bias,
                                               float* __restrict__ out){
  __shared__ float L[256 * 20];     // mat[:, b*16 .. b*16+16), row stride 20
  __shared__ float red[16][64];
  const int b = blockIdx.x >> 2, jc = blockIdx.x & 3;
  const int t = threadIdx.x, lane = t & 63, w = t >> 6;

  { // stage + reduce K-split partials: thread -> one float4 of L (coalesced)
    const int i = t >> 2, q = t & 3;
    const float* base = P + (size_t)b * 4096 + t * 4;
    float4 s0 = *(const float4*)(base);
    float4 s1 = *(const float4*)(base + 262144);
    float4 s2 = *(const float4*)(base + 524288);
    float4 s3 = *(const float4*)(base + 786432);
    float4 r;
    r.x = (s0.x + s1.x) + (s2.x + s3.x);
    r.y = (s0.y + s1.y) + (s2.y + s3.y);
    r.z = (s0.z + s1.z) + (s2.z + s3.z);
    r.w = (s0.w + s1.w) + (s2.w + s3.w);
    *(float4*)(&L[i * 20 + q * 4]) = r;
  }
  __syncthreads();

  const int j = jc * 64 + lane;
  float oj[16];
  #pragma unroll
  for (int q = 0; q < 4; ++q){
    float4 v = *(const float4*)(&L[j * 20 + q * 4]);
    oj[q*4+0] = v.x; oj[q*4+1] = v.y; oj[q*4+2] = v.z; oj[q*4+3] = v.w;
  }

  float acc = 0.f;
  const int i0 = w * 16;
  #pragma unroll 4
  for (int ii = i0; ii < i0 + 16; ++ii){
    const float4* fr = (const float4*)(&L[ii * 20]);   // wave-uniform -> broadcast
    float4 f0 = fr[0], f1 = fr[1], f2 = fr[2], f3 = fr[3];
    float p0 = fabsf(oj[0]  - f0.x) + fabsf(oj[1]  - f0.y)
             + fabsf(oj[2]  - f0.z) + fabsf(oj[3]  - f0.w);
    float p1 = fabsf(oj[4]  - f1.x) + fabsf(oj[5]  - f1.y)
             + fabsf(oj[6]  - f1.z) + fabsf(oj[7]  - f1.w);
    float p2 = fabsf(oj[8]  - f2.x) + fabsf(oj[9]  - f2.y)
             + fabsf(oj[10] - f2.z) + fabsf(oj[11] - f2.w);
    float p3 = fabsf(oj[12] - f3.x) + fabsf(oj[13] - f3.y)
             + fabsf(oj[14] - f3.z) + fabsf(oj[15] - f3.w);
    acc += exp2f(-LOG2E * ((p0 + p1) + (p2 + p3)));
  }
  red[w][lane] = acc;
  __syncthreads();
  if (w == 0){
    float tot = 0.f;
    #pragma unroll
    for (int ww = 0; ww < 16; ++ww) tot += red[ww][lane];
    out[(size_t)j * 64 + b] = tot + bias[b];
  }
}

extern "C" void kernel_launch(void* const* d_in, const int* in_sizes, int n_in,
                              void* d_out, int out_size, void* d_ws, size_t ws_size,
                              hipStream_t stream){
  const float* x    = (const float*)d_in[0];   // [256][1024]
  const float* W    = (const float*)d_in[1];   // [1024][1024] k-major
  const float* bias = (const float*)d_in[2];   // [64]
  float* out = (float*)d_out;                  // [256][64]
  float* P   = (float*)d_ws;                   // 4 MB: partial [4][64][256][16]

  k_gemm_ks<<<dim3(4, 16, 4), 256, 0, stream>>>(x, W, P);
  k_pair<<<256, 1024, 0, stream>>>(P, bias, out);
}

// Round 3
// 74.081 us; speedup vs baseline: 1.3661x; 1.0006x over previous
//
#include <hip/hip_runtime.h>
#include <hip/hip_bf16.h>

#define LOG2E 1.4426950408889634f

typedef __bf16 bf16x8 __attribute__((ext_vector_type(8)));
typedef float  f32x4  __attribute__((ext_vector_type(4)));

// 2 f32 -> packed 2x bf16 (RNE); compiler emits v_cvt_pk_bf16_f32
__device__ inline unsigned pack2(float lo, float hi){
  __hip_bfloat162 h = __float22bfloat162_rn(make_float2(lo, hi));
  return *reinterpret_cast<unsigned*>(&h);
}

// ---- K1: K-split GEMM, one-shot staging.  P[ks][b][i][c] f32 partial (b-major).
// grid (4 m, 16 n, 4 ks) = 256 blocks x 1024 thr (16 waves/CU vs 4 before).
// Each block stages its full 64x256 A-slice and 256x64 B-slice (bf16, W transposed,
// XOR-chunk swizzle) in ONE pass -> one barrier pair total (was 8).
// Thread group g = t>>8 runs the lineage 256-thread staging pattern on k-chunk g.
// Wave w (4x4 grid) computes one 16x16 output tile: 8 MFMAs over K=256.
__global__ __launch_bounds__(1024) void k_gemm_ks(const float* __restrict__ X,
                                                  const float* __restrict__ Wm,
                                                  float* __restrict__ P){
  __shared__ unsigned short As[4][64 * 72];   // [kchunk][m][k] bf16, row stride 72
  __shared__ unsigned short Bs[4][64 * 72];   // [kchunk][n][k] bf16, XOR-chunk swizzled
  const int m0 = blockIdx.x * 64, n0 = blockIdx.y * 64;
  const int k0 = blockIdx.z * 256;
  const int t = threadIdx.x;
  const int lane = t & 63, w = t >> 6;
  const int g = t >> 8, s = t & 255;          // k-chunk group, index within group
  const int r16 = lane & 15, quad = lane >> 4;
  const int wrow = (w & 3) * 16, wcol = (w >> 2) * 16;

  // global loads: 8x float4 per thread, all contiguous >=256B segments
  const int ar = s >> 2, aq = s & 3;          // A: row 0..63, 16-float quarter
  const int bc = s & 15, bg = s >> 4;         // B: 4-col group, 4-krow group
  const float* ap = X + (size_t)(m0 + ar) * 1024 + k0 + g * 64 + aq * 16;
  const float* bp = Wm + (size_t)(k0 + g * 64) * 1024 + n0 + bc * 4;

  float4 pa[4], pb[4];
  #pragma unroll
  for (int r = 0; r < 4; ++r) pa[r] = *(const float4*)(ap + r * 4);
  #pragma unroll
  for (int r = 0; r < 4; ++r) pb[r] = *(const float4*)(bp + (size_t)(4 * bg + r) * 1024);

  { // A tile: 16 floats -> 16 bf16, contiguous store
    unsigned short* d = &As[g][ar * 72 + aq * 16];
    uint4 o;
    o.x = pack2(pa[0].x, pa[0].y); o.y = pack2(pa[0].z, pa[0].w);
    o.z = pack2(pa[1].x, pa[1].y); o.w = pack2(pa[1].z, pa[1].w);
    *(uint4*)d = o;
    o.x = pack2(pa[2].x, pa[2].y); o.y = pack2(pa[2].z, pa[2].w);
    o.z = pack2(pa[3].x, pa[3].y); o.w = pack2(pa[3].z, pa[3].w);
    *(uint4*)(d + 8) = o;
  }
  { // B tile: transpose 4 k-rows x 4 n-cols into [n][k], swizzled 8-bf16 chunks
    #pragma unroll
    for (int e = 0; e < 4; ++e){
      const int n = bc * 4 + e;
      uint2 o;
      o.x = pack2(((const float*)&pb[0])[e], ((const float*)&pb[1])[e]);
      o.y = pack2(((const float*)&pb[2])[e], ((const float*)&pb[3])[e]);
      const int cw = (bg >> 1) ^ ((n >> 3) & 7);
      *(uint2*)(&Bs[g][n * 72 + cw * 8 + (bg & 1) * 4]) = o;
    }
  }
  __syncthreads();

  // two accumulators (kk-split) for a little MFMA ILP; summed at the end
  f32x4 acc0, acc1;
  #pragma unroll
  for (int e = 0; e < 4; ++e){ acc0[e] = 0.f; acc1[e] = 0.f; }
  const int nn = wcol + r16;
  const int nsw = (nn >> 3) & 7;
  #pragma unroll
  for (int gg = 0; gg < 4; ++gg){
    bf16x8 a0 = *(const bf16x8*)(&As[gg][(wrow + r16) * 72 + quad * 8]);
    bf16x8 a1 = *(const bf16x8*)(&As[gg][(wrow + r16) * 72 + 32 + quad * 8]);
    bf16x8 b0 = *(const bf16x8*)(&Bs[gg][nn * 72 + (((quad    ) ^ nsw) * 8)]);
    bf16x8 b1 = *(const bf16x8*)(&Bs[gg][nn * 72 + (((quad + 4) ^ nsw) * 8)]);
    acc0 = __builtin_amdgcn_mfma_f32_16x16x32_bf16(a0, b0, acc0, 0, 0, 0);
    acc1 = __builtin_amdgcn_mfma_f32_16x16x32_bf16(a1, b1, acc1, 0, 0, 0);
  }
  // C/D layout (verified): col = lane&15, row = (lane>>4)*4 + reg
  // b-major epilogue: P[ks][col>>4][row][col&15]; wave's b is constant
  float* Pz = P + (size_t)blockIdx.z * 64 * 4096 + (size_t)((n0 + wcol) >> 4) * 4096;
  #pragma unroll
  for (int r = 0; r < 4; ++r){
    const int row = m0 + wrow + quad * 4 + r;
    Pz[row * 16 + r16] = acc0[r] + acc1[r];
  }
}

// ---- K2: out[j][b] = bias[b] + sum_i exp(-sum_c |mat[i,b,c]-mat[j,b,c]|)
// grid 256 = 64 b * 4 j-chunks; 1024 thr = 16 waves; wave w owns i in [w*16,+16).
// Staging sums the 4 K-split partials from b-major P: four contiguous 16 KB
// streams per block (thread t -> P + b*4096 + t*4), fully coalesced.
__global__ __launch_bounds__(1024) void k_pair(const float* __restrict__ P,
                                               const float* __restrict__ bias,
                                               float* __restrict__ out){
  __shared__ float L[256 * 20];     // mat[:, b*16 .. b*16+16), row stride 20
  __shared__ float red[16][64];
  const int b = blockIdx.x >> 2, jc = blockIdx.x & 3;
  const int t = threadIdx.x, lane = t & 63, w = t >> 6;

  { // stage + reduce K-split partials: thread -> one float4 of L (coalesced)
    const int i = t >> 2, q = t & 3;
    const float* base = P + (size_t)b * 4096 + t * 4;
    float4 s0 = *(const float4*)(base);
    float4 s1 = *(const float4*)(base + 262144);
    float4 s2 = *(const float4*)(base + 524288);
    float4 s3 = *(const float4*)(base + 786432);
    float4 r;
    r.x = (s0.x + s1.x) + (s2.x + s3.x);
    r.y = (s0.y + s1.y) + (s2.y + s3.y);
    r.z = (s0.z + s1.z) + (s2.z + s3.z);
    r.w = (s0.w + s1.w) + (s2.w + s3.w);
    *(float4*)(&L[i * 20 + q * 4]) = r;
  }
  __syncthreads();

  const int j = jc * 64 + lane;
  float oj[16];
  #pragma unroll
  for (int q = 0; q < 4; ++q){
    float4 v = *(const float4*)(&L[j * 20 + q * 4]);
    oj[q*4+0] = v.x; oj[q*4+1] = v.y; oj[q*4+2] = v.z; oj[q*4+3] = v.w;
  }

  float acc = 0.f;
  const int i0 = w * 16;
  #pragma unroll 4
  for (int ii = i0; ii < i0 + 16; ++ii){
    const float4* fr = (const float4*)(&L[ii * 20]);   // wave-uniform -> broadcast
    float4 f0 = fr[0], f1 = fr[1], f2 = fr[2], f3 = fr[3];
    float p0 = fabsf(oj[0]  - f0.x) + fabsf(oj[1]  - f0.y)
             + fabsf(oj[2]  - f0.z) + fabsf(oj[3]  - f0.w);
    float p1 = fabsf(oj[4]  - f1.x) + fabsf(oj[5]  - f1.y)
             + fabsf(oj[6]  - f1.z) + fabsf(oj[7]  - f1.w);
    float p2 = fabsf(oj[8]  - f2.x) + fabsf(oj[9]  - f2.y)
             + fabsf(oj[10] - f2.z) + fabsf(oj[11] - f2.w);
    float p3 = fabsf(oj[12] - f3.x) + fabsf(oj[13] - f3.y)
             + fabsf(oj[14] - f3.z) + fabsf(oj[15] - f3.w);
    acc += exp2f(-LOG2E * ((p0 + p1) + (p2 + p3)));
  }
  red[w][lane] = acc;
  __syncthreads();
  if (w == 0){
    float tot = 0.f;
    #pragma unroll
    for (int ww = 0; ww < 16; ++ww) tot += red[ww][lane];
    out[(size_t)j * 64 + b] = tot + bias[b];
  }
}

extern "C" void kernel_launch(void* const* d_in, const int* in_sizes, int n_in,
                              void* d_out, int out_size, void* d_ws, size_t ws_size,
                              hipStream_t stream){
  const float* x    = (const float*)d_in[0];   // [256][1024]
  const float* W    = (const float*)d_in[1];   // [1024][1024] k-major
  const float* bias = (const float*)d_in[2];   // [64]
  float* out = (float*)d_out;                  // [256][64]
  float* P   = (float*)d_ws;                   // 4 MB: partial [4][64][256][16]

  k_gemm_ks<<<dim3(4, 16, 4), 1024, 0, stream>>>(x, W, P);
  k_pair<<<256, 1024, 0, stream>>>(P, bias, out);
}